// Round 1
// 162.905 us; speedup vs baseline: 1.0007x; 1.0007x over previous
//
#include <hip/hip_runtime.h>

// Causal GQA attention: S=2048, H=32, KVH=8, D=128, fp32 in/out.
// R5: (1) pre-pass converts K->bf16 and V->transposed bf16 in d_ws;
// (2) main kernel stages K/V tiles with global_load_lds (16B DMA, no VGPR
// round-trip, no ds_writes) into XOR-swizzled LDS layouts that are bank-uniform
// for the MFMA fragment reads despite the DMA's no-padding constraint;
// (3) PV uses 16x16x16 bf16 MFMA whose B-fragment IS the S^T C-layout ->
// the R3/R4 cross-quad shuffle network is deleted entirely;
// (4) LDS 64 KB double-buffered -> 2 blocks/CU, complementary-qt pairing.
// R6: latency attack (VGPR was 96 == no prefetch depth; all pipes <35%):
// (5) K-fragments software-pipelined 2-deep across nt (kf[2][4]);
// (6) V-fragments pipelined 2-deep across kt (vf[2][8]), kt=0 issued ahead
//     of the whole QK^T phase so V LDS latency hides under QK+softmax;
// (7) s_setprio(1) around the pure-MFMA bursts (T5).

#define SEQ   2048
#define NH    32
#define NKV   8
#define HD    128
#define QLD   4096      // NH*HD
#define KLD   1024      // NKV*HD
#define VT_HEAD (HD * SEQ)   // elems per kv-head in V^T

typedef __attribute__((ext_vector_type(8))) __bf16 bf16x8;
typedef __attribute__((ext_vector_type(4))) __bf16 bf16x4;
typedef __attribute__((ext_vector_type(2))) __bf16 bf16x2;
typedef __attribute__((ext_vector_type(4))) float  f32x4;
typedef __attribute__((ext_vector_type(4))) short  s16x4;
typedef __attribute__((ext_vector_type(2))) unsigned int u32x2;

static __device__ __forceinline__ unsigned int pack2(float lo, float hi) {
  bf16x2 t; t[0] = (__bf16)lo; t[1] = (__bf16)hi;
  return __builtin_bit_cast(unsigned int, t);
}

// PV matmul: D = A(V^T frag, 2 VGPR) * B(P frag = S^T C-layout regs) + C
static __device__ __forceinline__ f32x4 mfma16(bf16x4 a, u32x2 b, f32x4 c) {
#if __has_builtin(__builtin_amdgcn_mfma_f32_16x16x16bf16_1k)
  return __builtin_amdgcn_mfma_f32_16x16x16bf16_1k(
      __builtin_bit_cast(s16x4, a), __builtin_bit_cast(s16x4, b), c, 0, 0, 0);
#else
  asm volatile("v_mfma_f32_16x16x16_bf16 %0, %1, %2, %0"
               : "+v"(c) : "v"(a), "v"(b));
  return c;
#endif
}

// ---- pre-pass 1: K fp32 -> bf16, same [2048][1024] layout ----
__global__ void convert_k(const float* __restrict__ k, __bf16* __restrict__ kb) {
  const int i = (blockIdx.x * 256 + threadIdx.x) * 4;
  float4 v = *(const float4*)(k + i);
  bf16x4 b;
  b[0] = (__bf16)v.x; b[1] = (__bf16)v.y; b[2] = (__bf16)v.z; b[3] = (__bf16)v.w;
  *(bf16x4*)(kb + i) = b;
}

// ---- pre-pass 2: V fp32 [key][kvh*128+dim] -> bf16 V^T [kvh][dim][key] ----
__global__ void transpose_v(const float* __restrict__ v, __bf16* __restrict__ vt) {
  __shared__ __bf16 TT[HD][72];   // [dim][key(64)+pad]
  const int kvh = blockIdx.y;
  const int kb  = blockIdx.x * 64;
  const int t   = threadIdx.x;
  {
    const int key = t >> 2, dq = t & 3;
    const float* vp = v + (size_t)(kb + key) * KLD + kvh * HD + dq * 32;
#pragma unroll
    for (int j = 0; j < 8; ++j) {
      float4 x = *(const float4*)(vp + j * 4);
      const int d = dq * 32 + j * 4;
      TT[d + 0][key] = (__bf16)x.x; TT[d + 1][key] = (__bf16)x.y;
      TT[d + 2][key] = (__bf16)x.z; TT[d + 3][key] = (__bf16)x.w;
    }
  }
  __syncthreads();
  {
    const int dim = t >> 1, kh = (t & 1) * 32;
    __bf16* op = vt + (size_t)kvh * VT_HEAD + (size_t)dim * SEQ + kb + kh;
#pragma unroll
    for (int j = 0; j < 8; ++j)
      *(bf16x4*)(op + j * 4) = *(const bf16x4*)&TT[dim][kh + j * 4];
  }
}

// ---- main kernel ----
__global__ __launch_bounds__(256, 2)
void fa_kernel(const float* __restrict__ q, const __bf16* __restrict__ kg,
               const __bf16* __restrict__ vt, float* __restrict__ out) {
  // Swizzled tiles. K: slot = key*16 + (c8 ^ (key&7)), chunk = 8 bf16 of
  // K[key][c8*8..]. V: slot = dim*8 + (kc8 ^ (dim&7)), chunk = keys kc8*8..+7.
  __shared__ __bf16 KB[2][8192];   // 2 x 16 KB
  __shared__ __bf16 VB[2][8192];   // 2 x 16 KB

  const int head = blockIdx.x;
  const int yb   = blockIdx.y;
  const int qt   = (yb < 8) ? (15 - yb) : (yb - 8);  // co-resident pair sums 15
  const int kvh  = head >> 2;
  const int tid  = threadIdx.x;
  const int wave = tid >> 6;
  const int lane = tid & 63;
  const int l15  = lane & 15;
  const int quad = lane >> 4;
  const int h3   = l15 & 7;
  const int rw   = qt * 128 + wave * 32;

  constexpr float QS = 0.08838834764831845f * 1.4426950408889634f; // scale*log2e

  // Q fragments (B-operand of S^T = K*Q^T): B[k=quad*8+j][n=l15]
  bf16x8 qf[2][4];
#pragma unroll
  for (int sub = 0; sub < 2; ++sub) {
    const float* qp = q + (size_t)(rw + sub * 16 + l15) * QLD + head * HD + quad * 8;
#pragma unroll
    for (int c = 0; c < 4; ++c) {
      float4 a0 = *(const float4*)(qp + c * 32);
      float4 a1 = *(const float4*)(qp + c * 32 + 4);
      bf16x8 f;
      f[0] = (__bf16)(a0.x * QS); f[1] = (__bf16)(a0.y * QS);
      f[2] = (__bf16)(a0.z * QS); f[3] = (__bf16)(a0.w * QS);
      f[4] = (__bf16)(a1.x * QS); f[5] = (__bf16)(a1.y * QS);
      f[6] = (__bf16)(a1.z * QS); f[7] = (__bf16)(a1.w * QS);
      qf[sub][c] = f;
    }
  }

  // DMA lane->global offsets (elements). 4 K-instrs + 4 V-instrs per wave/tile.
  int kgo[4], vgo[4];
#pragma unroll
  for (int j = 0; j < 4; ++j) {
    const int key = (wave * 4 + j) * 4 + (lane >> 4);
    const int c8  = (lane & 15) ^ (key & 7);
    kgo[j] = key * KLD + kvh * HD + c8 * 8;
    const int dim = (wave * 4 + j) * 8 + (lane >> 3);
    const int kc8 = (lane & 7) ^ (dim & 7);
    vgo[j] = kvh * VT_HEAD + dim * SEQ + kc8 * 8;
  }

  auto dma_tile = [&](int kbase, int buf) {
#pragma unroll
    for (int j = 0; j < 4; ++j)
      __builtin_amdgcn_global_load_lds(
          (const __attribute__((address_space(1))) unsigned int*)(kg + kbase * KLD + kgo[j]),
          (__attribute__((address_space(3))) unsigned int*)&KB[buf][(wave * 4 + j) * 512],
          16, 0, 0);
#pragma unroll
    for (int j = 0; j < 4; ++j)
      __builtin_amdgcn_global_load_lds(
          (const __attribute__((address_space(1))) unsigned int*)(vt + kbase + vgo[j]),
          (__attribute__((address_space(3))) unsigned int*)&VB[buf][(wave * 4 + j) * 512],
          16, 0, 0);
  };

  // fragment byte offsets inside a buffer (bank-uniform by construction)
  int kaddr[4], vaddr[4];
#pragma unroll
  for (int c = 0; c < 4; ++c)
    kaddr[c] = l15 * 256 + (((c * 4 + quad) ^ h3) * 16);
#pragma unroll
  for (int kt = 0; kt < 4; ++kt)
    vaddr[kt] = l15 * 128 + (((kt * 2 + (quad >> 1)) ^ h3) * 16) + (quad & 1) * 8;

  f32x4 acc[2][8];
  f32x4 lp[2];
#pragma unroll
  for (int sub = 0; sub < 2; ++sub) {
    lp[sub] = (f32x4){0.f, 0.f, 0.f, 0.f};
#pragma unroll
    for (int nt = 0; nt < 8; ++nt) acc[sub][nt] = (f32x4){0.f, 0.f, 0.f, 0.f};
  }

  const int ntiles = 2 * qt + 2;
  dma_tile(0, 0);
  __syncthreads();   // barrier implies vmcnt(0): tile 0 staged

  for (int t = 0; t < ntiles; ++t) {
    const int buf = t & 1;
    if (t + 1 < ntiles) dma_tile((t + 1) * 64, buf ^ 1);  // overlaps compute

    const char* Kb = (const char*)&KB[buf][0];
    const char* Vb = (const char*)&VB[buf][0];

    // ---- software-pipelined fragment loads (R6) ----
    // kf: 2-deep across nt; vf: 2-deep across kt, kt=0 issued before QK^T so
    // its LDS latency hides under the whole QK+softmax phase.
    bf16x8 kf[2][4];
#pragma unroll
    for (int c = 0; c < 4; ++c)
      kf[0][c] = *(const bf16x8*)(Kb + kaddr[c]);            // nt=0 frags

    bf16x4 vf[2][8];
#pragma unroll
    for (int nt = 0; nt < 8; ++nt)
      vf[0][nt] = *(const bf16x4*)(Vb + vaddr[0] + nt * 2048);  // kt=0 frags

    // ---- S^T = K*Q^T (C-layout: key = quad*4+e, row = l15), then exp2 ----
    u32x2 pk[2][4];
#pragma unroll
    for (int nt = 0; nt < 4; ++nt) {
      if (nt < 3) {   // prefetch nt+1 K-fragments ahead of this nt's MFMAs
#pragma unroll
        for (int c = 0; c < 4; ++c)
          kf[(nt + 1) & 1][c] = *(const bf16x8*)(Kb + kaddr[c] + (nt + 1) * 4096);
      }
#pragma unroll
      for (int sub = 0; sub < 2; ++sub) {
        f32x4 s = (f32x4){0.f, 0.f, 0.f, 0.f};
        __builtin_amdgcn_s_setprio(1);
#pragma unroll
        for (int c = 0; c < 4; ++c)
          s = __builtin_amdgcn_mfma_f32_16x16x32_bf16(kf[nt & 1][c], qf[sub][c], s, 0, 0, 0);
        __builtin_amdgcn_s_setprio(0);
        if (t * 64 + 63 > rw + sub * 16) {        // causal mask (wave-uniform)
          const int key0  = t * 64 + nt * 16 + quad * 4;
          const int myrow = rw + sub * 16 + l15;
#pragma unroll
          for (int e = 0; e < 4; ++e)
            if (key0 + e > myrow) s[e] = -1e30f;
        }
        f32x4 p;
#pragma unroll
        for (int e = 0; e < 4; ++e) p[e] = __builtin_amdgcn_exp2f(s[e]);
        lp[sub] += p;
        u32x2 pkk;
        pkk.x = pack2(p[0], p[1]);
        pkk.y = pack2(p[2], p[3]);
        pk[sub][nt] = pkk;
      }
    }

    // ---- O^T += V^T * P  (16x16x16: B-frag = pk as-is, zero shuffles) ----
#pragma unroll
    for (int kt = 0; kt < 4; ++kt) {
      if (kt < 3) {   // prefetch kt+1 V-fragments ahead of this kt's MFMAs
#pragma unroll
        for (int nt = 0; nt < 8; ++nt)
          vf[(kt + 1) & 1][nt] = *(const bf16x4*)(Vb + vaddr[kt + 1] + nt * 2048);
      }
      __builtin_amdgcn_s_setprio(1);
#pragma unroll
      for (int nt = 0; nt < 8; ++nt) {
        acc[0][nt] = mfma16(vf[kt & 1][nt], pk[0][kt], acc[0][nt]);
        acc[1][nt] = mfma16(vf[kt & 1][nt], pk[1][kt], acc[1][nt]);
      }
      __builtin_amdgcn_s_setprio(0);
    }
    __syncthreads();   // drains next tile's DMA; frees buf for t+2
  }

  // ---- epilogue: lane owns row l15 entirely -> scalar inv, float4 stores ----
#pragma unroll
  for (int sub = 0; sub < 2; ++sub) {
    float ls = lp[sub][0] + lp[sub][1] + lp[sub][2] + lp[sub][3];
    ls += __shfl_xor(ls, 16);
    ls += __shfl_xor(ls, 32);
    const float inv = 1.0f / ls;
    float* op = out + (size_t)(rw + sub * 16 + l15) * QLD + head * HD + quad * 4;
#pragma unroll
    for (int nt = 0; nt < 8; ++nt) {
      f32x4 r = acc[sub][nt];
      float4 w = {r[0] * inv, r[1] * inv, r[2] * inv, r[3] * inv};
      *(float4*)(op + nt * 16) = w;
    }
  }
}

extern "C" void kernel_launch(void* const* d_in, const int* in_sizes, int n_in,
                              void* d_out, int out_size, void* d_ws, size_t ws_size,
                              hipStream_t stream) {
  const float* q = (const float*)d_in[0];
  const float* k = (const float*)d_in[1];
  const float* v = (const float*)d_in[2];
  float* o = (float*)d_out;
  __bf16* kbf = (__bf16*)d_ws;                    // 4 MB: K as bf16
  __bf16* vtb = (__bf16*)d_ws + (size_t)SEQ * KLD; // 4 MB: V^T bf16
  convert_k<<<2048, 256, 0, stream>>>(k, kbf);
  transpose_v<<<dim3(32, 8), 256, 0, stream>>>(v, vtb);
  fa_kernel<<<dim3(32, 16), 256, 0, stream>>>(q, kbf, vtb, o);
}

// Round 2
// 160.414 us; speedup vs baseline: 1.0162x; 1.0155x over previous
//
#include <hip/hip_runtime.h>

// Causal GQA attention: S=2048, H=32, KVH=8, D=128, fp32 in/out.
// R5: K->bf16 / V^T->bf16 pre-passes; global_load_lds staging into XOR-swizzled
// LDS; PV via 16x16x16 bf16 MFMA (B-frag == S^T C-layout, zero shuffles);
// 64 KB double-buffered LDS -> 2 blocks/CU.
// R6: kf/vf 2-deep software pipeline + s_setprio around MFMA bursts (neutral,
// kept).
// R7: WORK BALANCE. R5/R6 paired heavy+light blocks per CU, but the light
// block finished in ~2 tiles and the heavy one ran ~30 tiles SOLO ->
// time-avg occupancy 13% (4.26 waves/CU of 8). Now each block fuses the pair:
// wave sub0 = 16 rows of heavy 64-row tile (31-i), sub1 = 16 rows of light
// tile i. Per-wave work = (32-i)+(i+1) = 33 sub-units, identical for ALL 512
// blocks; sub1 switches off (block-uniform) for t > i. Costs +44% K/V
// staging/LDS reads (HBM at 10%, L2-resident), buys 2-blocks/CU for the whole
// kernel and synchronized completion.

#define SEQ   2048
#define NH    32
#define NKV   8
#define HD    128
#define QLD   4096      // NH*HD
#define KLD   1024      // NKV*HD
#define VT_HEAD (HD * SEQ)   // elems per kv-head in V^T

typedef __attribute__((ext_vector_type(8))) __bf16 bf16x8;
typedef __attribute__((ext_vector_type(4))) __bf16 bf16x4;
typedef __attribute__((ext_vector_type(2))) __bf16 bf16x2;
typedef __attribute__((ext_vector_type(4))) float  f32x4;
typedef __attribute__((ext_vector_type(4))) short  s16x4;
typedef __attribute__((ext_vector_type(2))) unsigned int u32x2;

static __device__ __forceinline__ unsigned int pack2(float lo, float hi) {
  bf16x2 t; t[0] = (__bf16)lo; t[1] = (__bf16)hi;
  return __builtin_bit_cast(unsigned int, t);
}

// PV matmul: D = A(V^T frag, 2 VGPR) * B(P frag = S^T C-layout regs) + C
static __device__ __forceinline__ f32x4 mfma16(bf16x4 a, u32x2 b, f32x4 c) {
#if __has_builtin(__builtin_amdgcn_mfma_f32_16x16x16bf16_1k)
  return __builtin_amdgcn_mfma_f32_16x16x16bf16_1k(
      __builtin_bit_cast(s16x4, a), __builtin_bit_cast(s16x4, b), c, 0, 0, 0);
#else
  asm volatile("v_mfma_f32_16x16x16_bf16 %0, %1, %2, %0"
               : "+v"(c) : "v"(a), "v"(b));
  return c;
#endif
}

// ---- pre-pass 1: K fp32 -> bf16, same [2048][1024] layout ----
__global__ void convert_k(const float* __restrict__ k, __bf16* __restrict__ kb) {
  const int i = (blockIdx.x * 256 + threadIdx.x) * 4;
  float4 v = *(const float4*)(k + i);
  bf16x4 b;
  b[0] = (__bf16)v.x; b[1] = (__bf16)v.y; b[2] = (__bf16)v.z; b[3] = (__bf16)v.w;
  *(bf16x4*)(kb + i) = b;
}

// ---- pre-pass 2: V fp32 [key][kvh*128+dim] -> bf16 V^T [kvh][dim][key] ----
__global__ void transpose_v(const float* __restrict__ v, __bf16* __restrict__ vt) {
  __shared__ __bf16 TT[HD][72];   // [dim][key(64)+pad]
  const int kvh = blockIdx.y;
  const int kb  = blockIdx.x * 64;
  const int t   = threadIdx.x;
  {
    const int key = t >> 2, dq = t & 3;
    const float* vp = v + (size_t)(kb + key) * KLD + kvh * HD + dq * 32;
#pragma unroll
    for (int j = 0; j < 8; ++j) {
      float4 x = *(const float4*)(vp + j * 4);
      const int d = dq * 32 + j * 4;
      TT[d + 0][key] = (__bf16)x.x; TT[d + 1][key] = (__bf16)x.y;
      TT[d + 2][key] = (__bf16)x.z; TT[d + 3][key] = (__bf16)x.w;
    }
  }
  __syncthreads();
  {
    const int dim = t >> 1, kh = (t & 1) * 32;
    __bf16* op = vt + (size_t)kvh * VT_HEAD + (size_t)dim * SEQ + kb + kh;
#pragma unroll
    for (int j = 0; j < 8; ++j)
      *(bf16x4*)(op + j * 4) = *(const bf16x4*)&TT[dim][kh + j * 4];
  }
}

// ---- main kernel ----
__global__ __launch_bounds__(256, 2)
void fa_kernel(const float* __restrict__ q, const __bf16* __restrict__ kg,
               const __bf16* __restrict__ vt, float* __restrict__ out) {
  // Swizzled tiles. K: slot = key*16 + (c8 ^ (key&7)), chunk = 8 bf16 of
  // K[key][c8*8..]. V: slot = dim*8 + (kc8 ^ (dim&7)), chunk = keys kc8*8..+7.
  __shared__ __bf16 KB[2][8192];   // 2 x 16 KB
  __shared__ __bf16 VB[2][8192];   // 2 x 16 KB

  const int head = blockIdx.x;
  const int ip   = blockIdx.y;          // pair index: light 64-row tile = ip,
                                        // heavy 64-row tile = 31-ip
  const int kvh  = head >> 2;
  const int tid  = threadIdx.x;
  const int wave = tid >> 6;
  const int lane = tid & 63;
  const int l15  = lane & 15;
  const int quad = lane >> 4;
  const int h3   = l15 & 7;

  // per-sub row bases: sub0 = heavy 16 rows, sub1 = light 16 rows
  const int rwS[2] = { (31 - ip) * 64 + wave * 16, ip * 64 + wave * 16 };

  constexpr float QS = 0.08838834764831845f * 1.4426950408889634f; // scale*log2e

  // Q fragments (B-operand of S^T = K*Q^T): B[k=quad*8+j][n=l15]
  bf16x8 qf[2][4];
#pragma unroll
  for (int sub = 0; sub < 2; ++sub) {
    const float* qp = q + (size_t)(rwS[sub] + l15) * QLD + head * HD + quad * 8;
#pragma unroll
    for (int c = 0; c < 4; ++c) {
      float4 a0 = *(const float4*)(qp + c * 32);
      float4 a1 = *(const float4*)(qp + c * 32 + 4);
      bf16x8 f;
      f[0] = (__bf16)(a0.x * QS); f[1] = (__bf16)(a0.y * QS);
      f[2] = (__bf16)(a0.z * QS); f[3] = (__bf16)(a0.w * QS);
      f[4] = (__bf16)(a1.x * QS); f[5] = (__bf16)(a1.y * QS);
      f[6] = (__bf16)(a1.z * QS); f[7] = (__bf16)(a1.w * QS);
      qf[sub][c] = f;
    }
  }

  // DMA lane->global offsets (elements). 4 K-instrs + 4 V-instrs per wave/tile.
  int kgo[4], vgo[4];
#pragma unroll
  for (int j = 0; j < 4; ++j) {
    const int key = (wave * 4 + j) * 4 + (lane >> 4);
    const int c8  = (lane & 15) ^ (key & 7);
    kgo[j] = key * KLD + kvh * HD + c8 * 8;
    const int dim = (wave * 4 + j) * 8 + (lane >> 3);
    const int kc8 = (lane & 7) ^ (dim & 7);
    vgo[j] = kvh * VT_HEAD + dim * SEQ + kc8 * 8;
  }

  auto dma_tile = [&](int kbase, int buf) {
#pragma unroll
    for (int j = 0; j < 4; ++j)
      __builtin_amdgcn_global_load_lds(
          (const __attribute__((address_space(1))) unsigned int*)(kg + kbase * KLD + kgo[j]),
          (__attribute__((address_space(3))) unsigned int*)&KB[buf][(wave * 4 + j) * 512],
          16, 0, 0);
#pragma unroll
    for (int j = 0; j < 4; ++j)
      __builtin_amdgcn_global_load_lds(
          (const __attribute__((address_space(1))) unsigned int*)(vt + kbase + vgo[j]),
          (__attribute__((address_space(3))) unsigned int*)&VB[buf][(wave * 4 + j) * 512],
          16, 0, 0);
  };

  // fragment byte offsets inside a buffer (bank-uniform by construction)
  int kaddr[4], vaddr[4];
#pragma unroll
  for (int c = 0; c < 4; ++c)
    kaddr[c] = l15 * 256 + (((c * 4 + quad) ^ h3) * 16);
#pragma unroll
  for (int kt = 0; kt < 4; ++kt)
    vaddr[kt] = l15 * 128 + (((kt * 2 + (quad >> 1)) ^ h3) * 16) + (quad & 1) * 8;

  f32x4 acc[2][8];
  f32x4 lp[2];
#pragma unroll
  for (int sub = 0; sub < 2; ++sub) {
    lp[sub] = (f32x4){0.f, 0.f, 0.f, 0.f};
#pragma unroll
    for (int nt = 0; nt < 8; ++nt) acc[sub][nt] = (f32x4){0.f, 0.f, 0.f, 0.f};
  }

  const int ntiles = 32 - ip;   // heavy tile (31-ip) needs key tiles 0..31-ip
  dma_tile(0, 0);
  __syncthreads();   // barrier implies vmcnt(0): tile 0 staged

  for (int t = 0; t < ntiles; ++t) {
    const int buf = t & 1;
    if (t + 1 < ntiles) dma_tile((t + 1) * 64, buf ^ 1);  // overlaps compute

    const bool light_on = (t <= ip);   // block-uniform: light rows still active
    const char* Kb = (const char*)&KB[buf][0];
    const char* Vb = (const char*)&VB[buf][0];

    // ---- software-pipelined fragment loads (R6) ----
    bf16x8 kf[2][4];
#pragma unroll
    for (int c = 0; c < 4; ++c)
      kf[0][c] = *(const bf16x8*)(Kb + kaddr[c]);            // nt=0 frags

    bf16x4 vf[2][8];
#pragma unroll
    for (int nt = 0; nt < 8; ++nt)
      vf[0][nt] = *(const bf16x4*)(Vb + vaddr[0] + nt * 2048);  // kt=0 frags

    // ---- S^T = K*Q^T (C-layout: key = quad*4+e, row = l15), then exp2 ----
    u32x2 pk[2][4];
#pragma unroll
    for (int nt = 0; nt < 4; ++nt) {
      if (nt < 3) {   // prefetch nt+1 K-fragments ahead of this nt's MFMAs
#pragma unroll
        for (int c = 0; c < 4; ++c)
          kf[(nt + 1) & 1][c] = *(const bf16x8*)(Kb + kaddr[c] + (nt + 1) * 4096);
      }
#pragma unroll
      for (int sub = 0; sub < 2; ++sub) {
        if (sub == 1 && !light_on) continue;   // block-uniform skip
        f32x4 s = (f32x4){0.f, 0.f, 0.f, 0.f};
        __builtin_amdgcn_s_setprio(1);
#pragma unroll
        for (int c = 0; c < 4; ++c)
          s = __builtin_amdgcn_mfma_f32_16x16x32_bf16(kf[nt & 1][c], qf[sub][c], s, 0, 0, 0);
        __builtin_amdgcn_s_setprio(0);
        if (t * 64 + 63 > rwS[sub]) {          // causal mask (wave-uniform)
          const int key0  = t * 64 + nt * 16 + quad * 4;
          const int myrow = rwS[sub] + l15;
#pragma unroll
          for (int e = 0; e < 4; ++e)
            if (key0 + e > myrow) s[e] = -1e30f;
        }
        f32x4 p;
#pragma unroll
        for (int e = 0; e < 4; ++e) p[e] = __builtin_amdgcn_exp2f(s[e]);
        lp[sub] += p;
        u32x2 pkk;
        pkk.x = pack2(p[0], p[1]);
        pkk.y = pack2(p[2], p[3]);
        pk[sub][nt] = pkk;
      }
    }

    // ---- O^T += V^T * P  (16x16x16: B-frag = pk as-is, zero shuffles) ----
#pragma unroll
    for (int kt = 0; kt < 4; ++kt) {
      if (kt < 3) {   // prefetch kt+1 V-fragments ahead of this kt's MFMAs
#pragma unroll
        for (int nt = 0; nt < 8; ++nt)
          vf[(kt + 1) & 1][nt] = *(const bf16x4*)(Vb + vaddr[kt + 1] + nt * 2048);
      }
      __builtin_amdgcn_s_setprio(1);
#pragma unroll
      for (int nt = 0; nt < 8; ++nt) {
        acc[0][nt] = mfma16(vf[kt & 1][nt], pk[0][kt], acc[0][nt]);
        if (light_on)
          acc[1][nt] = mfma16(vf[kt & 1][nt], pk[1][kt], acc[1][nt]);
      }
      __builtin_amdgcn_s_setprio(0);
    }
    __syncthreads();   // drains next tile's DMA; frees buf for t+2
  }

  // ---- epilogue: lane owns row l15 entirely -> scalar inv, float4 stores ----
#pragma unroll
  for (int sub = 0; sub < 2; ++sub) {
    float ls = lp[sub][0] + lp[sub][1] + lp[sub][2] + lp[sub][3];
    ls += __shfl_xor(ls, 16);
    ls += __shfl_xor(ls, 32);
    const float inv = 1.0f / ls;
    float* op = out + (size_t)(rwS[sub] + l15) * QLD + head * HD + quad * 4;
#pragma unroll
    for (int nt = 0; nt < 8; ++nt) {
      f32x4 r = acc[sub][nt];
      float4 w = {r[0] * inv, r[1] * inv, r[2] * inv, r[3] * inv};
      *(float4*)(op + nt * 16) = w;
    }
  }
}

extern "C" void kernel_launch(void* const* d_in, const int* in_sizes, int n_in,
                              void* d_out, int out_size, void* d_ws, size_t ws_size,
                              hipStream_t stream) {
  const float* q = (const float*)d_in[0];
  const float* k = (const float*)d_in[1];
  const float* v = (const float*)d_in[2];
  float* o = (float*)d_out;
  __bf16* kbf = (__bf16*)d_ws;                    // 4 MB: K as bf16
  __bf16* vtb = (__bf16*)d_ws + (size_t)SEQ * KLD; // 4 MB: V^T bf16
  convert_k<<<2048, 256, 0, stream>>>(k, kbf);
  transpose_v<<<dim3(32, 8), 256, 0, stream>>>(v, vtb);
  fa_kernel<<<dim3(32, 16), 256, 0, stream>>>(q, kbf, vtb, o);
}